// Round 4
// baseline (21256.683 us; speedup 1.0000x reference)
//
#include <hip/hip_runtime.h>

#define NTHR 1024
#define NB   16
#define NOSC 50
#define NPER 40
#define KTOT 2000
#define KPAD 2048
#define NSTEP 700
#define BATCH 4096
#define B1STR 36
#define HALF_PI 1.57079632679489662f
#define ACT_OFF ((size_t)NSTEP * BATCH * 4)

typedef _Float16 v8h __attribute__((ext_vector_type(8)));
typedef float v4f __attribute__((ext_vector_type(4)));

__device__ _Float16 g_w4[32 * KPAD];    // fc4_w in f16, zero-padded K 2000->2048

__device__ __forceinline__ float dot4(float4 a, float4 b, float acc) {
    acc = fmaf(a.x, b.x, acc);
    acc = fmaf(a.y, b.y, acc);
    acc = fmaf(a.z, b.z, acc);
    acc = fmaf(a.w, b.w, acc);
    return acc;
}

__global__ void prep_f16(const float* __restrict__ fc4_w) {
    int tid = blockIdx.x * blockDim.x + threadIdx.x;   // 65536 total
    int j = tid >> 11, k = tid & 2047;
    g_w4[j * KPAD + k] = (k < KTOT) ? (_Float16)fc4_w[j * KTOT + k] : (_Float16)0.f;
}

// act layout (A-fragment-major, per k-step block of 32 k):
//   element (b, k): oct = k>>3, j = k&7, slot = b ^ (oct & 15)
//   f16 idx = (oct>>2)*512 + (oct&3)*128 + slot*8 + j
// A-frag read for (m=lane&15, ks, quad=lane>>4): oct = ks*4+quad,
//   idx = ks*512 + quad*128 + ((m ^ (oct&15)))*8
__global__ __launch_bounds__(NTHR)
__attribute__((amdgpu_waves_per_eu(4, 4)))
void net_main(const float* __restrict__ x,
              const float* __restrict__ fc1_w, const float* __restrict__ fc1_b,
              const float* __restrict__ fc2_w, const float* __restrict__ fc2_b,
              const float* __restrict__ fc3_w, const float* __restrict__ fc3_b,
              const float* __restrict__ fcd_w, const float* __restrict__ fcd_b,
              const float* __restrict__ enc,   const float* __restrict__ osc_bias,
              const float* __restrict__ dec,
              const float* __restrict__ fc4_b,
              const float* __restrict__ fc5_w, const float* __restrict__ fc5_b,
              float* __restrict__ out)
{
    __shared__ __align__(16) _Float16 act_sh[64 * 512];   // 64 KB, frag-major
    __shared__ __align__(16) float part[16 * 2 * 256];    // 32 KB, MFMA partials
    __shared__ __align__(16) float dpart[50 * 164 + 16];  // deriv partials
    __shared__ __align__(16) float os_sh[NOSC * NB * 2];  // [o][b*2+d]
    __shared__ __align__(16) float b1s[NB * B1STR];
    __shared__ __align__(16) float dir[NB * 2];

    const int t    = threadIdx.x;
    const int lane = t & 63;
    const int wv   = t >> 6;            // 0..15
    const int b0   = blockIdx.x * NB;

    float* h  = (float*)act_sh;         // [NB][128] f32 temp (pre-loop only)
    float* h2 = (float*)act_sh + NB * 128;

    // ---------- precompute: fc1 ----------
    #pragma unroll
    for (int ii = 0; ii < 2; ++ii) {
        int task = t + ii * NTHR;       // 2048 tasks
        int b = task >> 7, i = task & 127;
        float x0 = x[(b0 + b) * 2 + 0];
        float x1 = x[(b0 + b) * 2 + 1];
        float v = fmaf(x0, fc1_w[2 * i], fmaf(x1, fc1_w[2 * i + 1], fc1_b[i]));
        h[b * 128 + i] = fmaxf(v, 0.f);
    }
    __syncthreads();
    // ---------- precompute: fc2 -> h2, fcd -> dir ----------
    #pragma unroll
    for (int ii = 0; ii < 2; ++ii) {
        int task = t + ii * NTHR;
        int b = task >> 7, i = task & 127;
        float acc = fc2_b[i];
        #pragma unroll 4
        for (int k = 0; k < 128; k += 4)
            acc = dot4(*(const float4*)&fc2_w[i * 128 + k],
                       *(const float4*)&h[b * 128 + k], acc);
        h2[b * 128 + i] = fmaxf(acc, 0.f);
    }
    if (t < NB * 2) {
        int b = t >> 1, j = t & 1;
        float acc = fcd_b[j];
        #pragma unroll 4
        for (int k = 0; k < 128; k += 4)
            acc = dot4(*(const float4*)&fcd_w[j * 128 + k],
                       *(const float4*)&h[b * 128 + k], acc);
        dir[b * 2 + j] = acc;
    }
    __syncthreads();
    // ---------- precompute: fc3 -> os_sh ----------
    #pragma unroll
    for (int ii = 0; ii < 2; ++ii) {
        int task = t + ii * NTHR;
        if (task < NOSC * NB * 2) {     // 1600 tasks
            int o = task >> 5, r = task & 31, b = r >> 1;
            int row = o * 2 + (r & 1);
            float acc = fc3_b[row];
            #pragma unroll 4
            for (int k = 0; k < 128; k += 4)
                acc = dot4(*(const float4*)&fc3_w[row * 128 + k],
                           *(const float4*)&h2[b * 128 + k], acc);
            os_sh[o * 32 + r] = acc;
        }
    }
    // ---------- limb init ----------
    float theta = 0.f, omega = 0.f, l1 = 0.f, l2 = 0.f, bs0 = 0.f, bs1 = 0.f;
    if (t < NB) {
        theta = x[(b0 + t) * 2 + 0];
        l1 = fmaf(-0.02f, theta, 0.1f);
        l2 = fmaf( 0.02f, theta, 0.1f);
    }
    __syncthreads();
    if (t < NB) {
        bs0 = dir[t * 2 + 0] + fc5_b[0];
        bs1 = dir[t * 2 + 1] + fc5_b[1];
    }
    // zero act padding (octets 250..255 -> f16 idx [32000, 32768))
    if (t < 768) act_sh[32000 + t] = (_Float16)0.f;

    // ---------- persistent B-fragments: wave wv owns ksteps wv*4 .. wv*4+3 ----------
    const int n_col = lane & 15, quad = lane >> 4;
    v8h bw[4][2];
    #pragma unroll
    for (int ks4 = 0; ks4 < 4; ++ks4)
        #pragma unroll
        for (int nt = 0; nt < 2; ++nt)
            bw[ks4][nt] = *(const v8h*)&g_w4[(nt * 16 + n_col) * KPAD +
                                             ((wv * 4 + ks4) * 32 + quad * 8)];
    // A-frag LDS offsets (f16 idx), slot swizzle independent of wv
    int a_off[4];
    #pragma unroll
    for (int ks4 = 0; ks4 < 4; ++ks4) {
        int oct15 = (ks4 * 4 + quad) & 15;
        a_off[ks4] = (wv * 4 + ks4) * 512 + quad * 128 + ((n_col ^ oct15) * 8);
    }
    __syncthreads();

    for (int s = 0; s < NSTEP; ++s) {
        // ---- phase A: act (f16 frag-major) + deriv partials ----
        #pragma unroll
        for (int ii = 0; ii < 4; ++ii) {
            int task = t + ii * NTHR;           // 4096 tasks
            int oct = task & 255;
            int b   = task >> 8;                // 0..15
            if (oct < 250) {
                int o = oct / 5;
                int c = oct - o * 5;
                float os0 = os_sh[o * 32 + b * 2 + 0];
                float os1 = os_sh[o * 32 + b * 2 + 1];
                float4 e0 = *(const float4*)&enc[oct * 16 + 0];
                float4 e1 = *(const float4*)&enc[oct * 16 + 4];
                float4 e2 = *(const float4*)&enc[oct * 16 + 8];
                float4 e3 = *(const float4*)&enc[oct * 16 + 12];
                float4 bi0 = *(const float4*)&osc_bias[oct * 8 + 0];
                float4 bi1 = *(const float4*)&osc_bias[oct * 8 + 4];
                float r0 = fmaxf(fmaf(e0.x, os0, fmaf(e0.y, os1, bi0.x)), 0.f);
                float r1 = fmaxf(fmaf(e0.z, os0, fmaf(e0.w, os1, bi0.y)), 0.f);
                float r2 = fmaxf(fmaf(e1.x, os0, fmaf(e1.y, os1, bi0.z)), 0.f);
                float r3 = fmaxf(fmaf(e1.z, os0, fmaf(e1.w, os1, bi0.w)), 0.f);
                float r4 = fmaxf(fmaf(e2.x, os0, fmaf(e2.y, os1, bi1.x)), 0.f);
                float r5 = fmaxf(fmaf(e2.z, os0, fmaf(e2.w, os1, bi1.y)), 0.f);
                float r6 = fmaxf(fmaf(e3.x, os0, fmaf(e3.y, os1, bi1.z)), 0.f);
                float r7 = fmaxf(fmaf(e3.z, os0, fmaf(e3.w, os1, bi1.w)), 0.f);
                v8h pk;
                pk[0] = (_Float16)r0; pk[1] = (_Float16)r1;
                pk[2] = (_Float16)r2; pk[3] = (_Float16)r3;
                pk[4] = (_Float16)r4; pk[5] = (_Float16)r5;
                pk[6] = (_Float16)r6; pk[7] = (_Float16)r7;
                int slot = (b ^ oct) & 15;
                *(v8h*)&act_sh[(oct >> 2) * 512 + (oct & 3) * 128 + slot * 8] = pk;
                // deriv partials (f32)
                const float* dr = &dec[o * 80 + c * 8];
                float4 d00 = *(const float4*)&dr[0];
                float4 d01 = *(const float4*)&dr[4];
                float4 d10 = *(const float4*)&dr[40];
                float4 d11 = *(const float4*)&dr[44];
                float p0 = fmaf(r0, d00.x, fmaf(r1, d00.y, fmaf(r2, d00.z, fmaf(r3, d00.w,
                           fmaf(r4, d01.x, fmaf(r5, d01.y, fmaf(r6, d01.z, r7 * d01.w)))))));
                float p1 = fmaf(r0, d10.x, fmaf(r1, d10.y, fmaf(r2, d10.z, fmaf(r3, d10.w,
                           fmaf(r4, d11.x, fmaf(r5, d11.y, fmaf(r6, d11.z, r7 * d11.w)))))));
                dpart[o * 164 + b * 10 + 0 + c] = p0;
                dpart[o * 164 + b * 10 + 5 + c] = p1;
            }
        }
        __syncthreads();

        // ---- phase B: MFMA over this wave's 4 ksteps ----
        {
            v4f c0 = {0.f, 0.f, 0.f, 0.f}, c1 = {0.f, 0.f, 0.f, 0.f};
            #pragma unroll
            for (int ks4 = 0; ks4 < 4; ++ks4) {
                v8h a = *(const v8h*)&act_sh[a_off[ks4]];
                c0 = __builtin_amdgcn_mfma_f32_16x16x32_f16(a, bw[ks4][0], c0, 0, 0, 0);
                c1 = __builtin_amdgcn_mfma_f32_16x16x32_f16(a, bw[ks4][1], c1, 0, 0, 0);
            }
            *(v4f*)&part[(wv * 2 + 0) * 256 + lane * 4] = c0;
            *(v4f*)&part[(wv * 2 + 1) * 256 + lane * 4] = c1;
        }
        // ---- deriv reduce: os += DT * sum(dpart) ----
        #pragma unroll
        for (int ii = 0; ii < 2; ++ii) {
            int task = t + ii * NTHR;
            if (task < NOSC * NB * 2) {         // 1600 tasks
                int o = task >> 5, r = task & 31, b = r >> 1, d = r & 1;
                const float* dp = &dpart[o * 164 + b * 10 + d * 5];
                float sdv = ((dp[0] + dp[1]) + (dp[2] + dp[3])) + dp[4];
                os_sh[o * 32 + r] += 0.001f * sdv;
            }
        }
        __syncthreads();

        // ---- R: reduce MFMA partials over 16 waves -> b1 ----
        if (t < 512) {
            int b = t & 15, j = t >> 4;         // b 0..15, j 0..31
            int base = (j >> 4) * 256 + (b >> 2) * 64 + (j & 15) * 4 + (b & 3);
            float sum = 0.f;
            #pragma unroll
            for (int w = 0; w < 16; ++w)
                sum += part[w * 512 + base];
            b1s[b * B1STR + j] = fmaxf(sum + fc4_b[j], 0.f);
        }
        __syncthreads();

        // ---- phase C: fc5 + limb ODE + stores (threads 0..15) ----
        if (t < NB) {
            float a0 = bs0, a1 = bs1;
            #pragma unroll
            for (int i = 0; i < 32; i += 4) {
                float4 bv = *(const float4*)&b1s[t * B1STR + i];
                a0 = dot4(bv, *(const float4*)&fc5_w[i],      a0);
                a1 = dot4(bv, *(const float4*)&fc5_w[32 + i], a1);
            }
            float f1v = fmaxf(a0, 0.f) * 50.f * fmaxf(l1 - 0.05f, 0.f);
            float f2v = fmaxf(a1, 0.f) * 50.f * fmaxf(l2 - 0.05f, 0.f);
            float domega = (0.02f * (f2v - f1v) - 0.01f * omega) / 0.001f;
            float dl1 = ((0.1f - 0.02f * theta) - l1) / 0.05f;
            float dl2 = ((0.1f + 0.02f * theta) - l2) / 0.05f;
            float pos = fmaf(0.001f, omega,  theta);
            float vel = fmaf(0.001f, domega, omega);
            l1 = fmaf(0.001f, dl1, l1);
            l2 = fmaf(0.001f, dl2, l2);
            bool inb = (pos > -HALF_PI) && (pos < HALF_PI);
            float posc = fminf(fmaxf(pos, -HALF_PI), HALF_PI);
            vel = inb ? vel : 0.f;
            theta = posc;
            omega = vel;
            float4 lo; lo.x = posc; lo.y = vel; lo.z = l1; lo.w = l2;
            *(float4*)&out[((size_t)s * BATCH + (b0 + t)) * 4] = lo;
            float2 ao; ao.x = a0; ao.y = a1;
            *(float2*)&out[ACT_OFF + ((size_t)s * BATCH + (b0 + t)) * 2] = ao;
        }
        __syncthreads();
    }
}

extern "C" void kernel_launch(void* const* d_in, const int* in_sizes, int n_in,
                              void* d_out, int out_size, void* d_ws, size_t ws_size,
                              hipStream_t stream) {
    (void)in_sizes; (void)n_in; (void)d_ws; (void)ws_size; (void)out_size;
    const float* x_     = (const float*)d_in[0];
    const float* fc1_w  = (const float*)d_in[1];
    const float* fc1_b  = (const float*)d_in[2];
    const float* fc2_w  = (const float*)d_in[3];
    const float* fc2_b  = (const float*)d_in[4];
    const float* fc3_w  = (const float*)d_in[5];
    const float* fc3_b  = (const float*)d_in[6];
    const float* fcd_w  = (const float*)d_in[7];
    const float* fcd_b  = (const float*)d_in[8];
    const float* enc    = (const float*)d_in[9];
    const float* oscb   = (const float*)d_in[10];
    const float* dec    = (const float*)d_in[11];
    const float* fc4_w  = (const float*)d_in[12];
    const float* fc4_b  = (const float*)d_in[13];
    const float* fc5_w  = (const float*)d_in[14];
    const float* fc5_b  = (const float*)d_in[15];
    float* out = (float*)d_out;

    hipLaunchKernelGGL(prep_f16, dim3(256), dim3(256), 0, stream, fc4_w);
    hipLaunchKernelGGL(net_main, dim3(BATCH / NB), dim3(NTHR), 0, stream,
                       x_, fc1_w, fc1_b, fc2_w, fc2_b, fc3_w, fc3_b,
                       fcd_w, fcd_b, enc, oscb, dec, fc4_b,
                       fc5_w, fc5_b, out);
}

// Round 5
// 4260.089 us; speedup vs baseline: 4.9897x; 4.9897x over previous
//
#include <hip/hip_runtime.h>

#define NTHR 1024
#define NB   16
#define NOSC 50
#define NPER 40
#define KTOT 2000
#define KPAD 2048
#define NSTEP 700
#define BATCH 4096
#define B1STR 36
#define HALF_PI 1.57079632679489662f
#define ACT_OFF ((size_t)NSTEP * BATCH * 4)

typedef _Float16 v8h __attribute__((ext_vector_type(8)));
typedef _Float16 h2_t __attribute__((ext_vector_type(2)));
typedef float v4f __attribute__((ext_vector_type(4)));

__device__ _Float16 g_w4[32 * KPAD];    // fc4_w in f16, zero-padded K 2000->2048

__device__ __forceinline__ float fdot2f(float a_bits, float b_bits, float acc) {
    h2_t a = __builtin_bit_cast(h2_t, a_bits);
    h2_t b = __builtin_bit_cast(h2_t, b_bits);
#if __has_builtin(__builtin_amdgcn_fdot2)
    return __builtin_amdgcn_fdot2(a, b, acc, false);
#else
    return fmaf((float)a[0], (float)b[0], fmaf((float)a[1], (float)b[1], acc));
#endif
}

__device__ __forceinline__ float dot4(float4 a, float4 b, float acc) {
    acc = fmaf(a.x, b.x, acc);
    acc = fmaf(a.y, b.y, acc);
    acc = fmaf(a.z, b.z, acc);
    acc = fmaf(a.w, b.w, acc);
    return acc;
}

__device__ __forceinline__ float pkrtz(float a, float b) {
    auto q = __builtin_amdgcn_cvt_pkrtz(a, b);
    return __builtin_bit_cast(float, q);
}

__global__ void prep_f16(const float* __restrict__ fc4_w) {
    int tid = blockIdx.x * blockDim.x + threadIdx.x;   // 65536 total
    int j = tid >> 11, k = tid & 2047;
    g_w4[j * KPAD + k] = (k < KTOT) ? (_Float16)fc4_w[j * KTOT + k] : (_Float16)0.f;
}

// act layout (A-fragment-major, per k-step block of 32 k):
//   element (b, k): oct = k>>3, j = k&7, slot = b ^ (oct & 15)
//   f16 idx = (oct>>2)*512 + (oct&3)*128 + slot*8 + j
// A-frag read for (m=lane&15, ks, quad=lane>>4): oct = ks*4+quad,
//   idx = ks*512 + quad*128 + ((m ^ (oct&15)))*8
__global__ __launch_bounds__(NTHR)
void net_main(const float* __restrict__ x,
              const float* __restrict__ fc1_w, const float* __restrict__ fc1_b,
              const float* __restrict__ fc2_w, const float* __restrict__ fc2_b,
              const float* __restrict__ fc3_w, const float* __restrict__ fc3_b,
              const float* __restrict__ fcd_w, const float* __restrict__ fcd_b,
              const float* __restrict__ enc,   const float* __restrict__ osc_bias,
              const float* __restrict__ dec,
              const float* __restrict__ fc4_b,
              const float* __restrict__ fc5_w, const float* __restrict__ fc5_b,
              float* __restrict__ out)
{
    __shared__ __align__(16) _Float16 act_sh[64 * 512];   // 64 KB, frag-major
    __shared__ __align__(16) float part[16 * 2 * 256];    // 32 KB, MFMA partials
    __shared__ __align__(16) float os_sh[NOSC * NB * 2];  // 6.4 KB [o][b*2+d]
    __shared__ __align__(16) float enc_sh[4096];          // 16 KB, [oct*16+..]
    __shared__ __align__(16) float bias_sh[2048];         // 8 KB, [oct*8+j]
    __shared__ __align__(16) _Float16 dec_sh[4096];       // 8 KB, [(o*2+d)*40+p]
    __shared__ __align__(16) float b1s[NB * B1STR];
    __shared__ __align__(16) float dir[NB * 2];

    const int t    = threadIdx.x;
    const int lane = t & 63;
    const int wv   = t >> 6;            // 0..15
    const int b0   = blockIdx.x * NB;

    float* h  = (float*)act_sh;         // [NB][128] f32 temp (pre-loop only)
    float* h2 = (float*)act_sh + NB * 128;

    // ---------- stage constants to LDS ----------
    for (int i = t; i < 4000; i += NTHR) enc_sh[i]  = enc[i];
    for (int i = t; i < 2000; i += NTHR) bias_sh[i] = osc_bias[i];
    for (int i = t; i < 4000; i += NTHR) dec_sh[i]  = (_Float16)dec[i];

    // ---------- precompute: fc1 ----------
    #pragma unroll
    for (int ii = 0; ii < 2; ++ii) {
        int task = t + ii * NTHR;       // 2048 tasks
        int b = task >> 7, i = task & 127;
        float x0 = x[(b0 + b) * 2 + 0];
        float x1 = x[(b0 + b) * 2 + 1];
        float v = fmaf(x0, fc1_w[2 * i], fmaf(x1, fc1_w[2 * i + 1], fc1_b[i]));
        h[b * 128 + i] = fmaxf(v, 0.f);
    }
    __syncthreads();
    // ---------- precompute: fc2 -> h2, fcd -> dir ----------
    #pragma unroll
    for (int ii = 0; ii < 2; ++ii) {
        int task = t + ii * NTHR;
        int b = task >> 7, i = task & 127;
        float acc = fc2_b[i];
        #pragma unroll 4
        for (int k = 0; k < 128; k += 4)
            acc = dot4(*(const float4*)&fc2_w[i * 128 + k],
                       *(const float4*)&h[b * 128 + k], acc);
        h2[b * 128 + i] = fmaxf(acc, 0.f);
    }
    if (t < NB * 2) {
        int b = t >> 1, j = t & 1;
        float acc = fcd_b[j];
        #pragma unroll 4
        for (int k = 0; k < 128; k += 4)
            acc = dot4(*(const float4*)&fcd_w[j * 128 + k],
                       *(const float4*)&h[b * 128 + k], acc);
        dir[b * 2 + j] = acc;
    }
    __syncthreads();
    // ---------- precompute: fc3 -> os_sh ----------
    #pragma unroll
    for (int ii = 0; ii < 2; ++ii) {
        int task = t + ii * NTHR;
        if (task < NOSC * NB * 2) {     // 1600 tasks
            int o = task >> 5, r = task & 31, b = r >> 1;
            int row = o * 2 + (r & 1);
            float acc = fc3_b[row];
            #pragma unroll 4
            for (int k = 0; k < 128; k += 4)
                acc = dot4(*(const float4*)&fc3_w[row * 128 + k],
                           *(const float4*)&h2[b * 128 + k], acc);
            os_sh[o * 32 + r] = acc;
        }
    }
    // ---------- limb init ----------
    float theta = 0.f, omega = 0.f, l1 = 0.f, l2 = 0.f, bs0 = 0.f, bs1 = 0.f;
    if (t < NB) {
        theta = x[(b0 + t) * 2 + 0];
        l1 = fmaf(-0.02f, theta, 0.1f);
        l2 = fmaf( 0.02f, theta, 0.1f);
    }
    __syncthreads();
    if (t < NB) {
        bs0 = dir[t * 2 + 0] + fc5_b[0];
        bs1 = dir[t * 2 + 1] + fc5_b[1];
    }
    // zero act padding (octets 250..255 -> f16 idx [32000, 32768))
    if (t < 768) act_sh[32000 + t] = (_Float16)0.f;

    // ---------- loop-invariant indices ----------
    const int n_col = lane & 15, quad = lane >> 4;
    const _Float16* wp = &g_w4[n_col * KPAD + wv * 128 + quad * 8];  // + ks4*32; +16*KPAD for nt=1
    int a_off[4];
    #pragma unroll
    for (int ks4 = 0; ks4 < 4; ++ks4) {
        int oct15 = ((wv * 4 + ks4) * 4 + quad) & 15;
        a_off[ks4] = (wv * 4 + ks4) * 512 + quad * 128 + ((n_col ^ oct15) * 8);
    }
    __syncthreads();

    for (int s = 0; s < NSTEP; ++s) {
        // ---- phase A: act = relu(enc . os + bias) -> f16 frag-major ----
        // task = ii*1024 + t: b = task&15 (lane-major -> enc broadcast), oct = task>>4
        #pragma unroll
        for (int ii = 0; ii < 4; ++ii) {
            int task = t + ii * NTHR;
            int oct = task >> 4;            // 0..255
            int b   = task & 15;
            if (oct < 250) {
                int o = oct / 5;
                float os0 = os_sh[o * 32 + b * 2 + 0];
                float os1 = os_sh[o * 32 + b * 2 + 1];
                const float* ep = &enc_sh[oct * 16];
                const float* bp = &bias_sh[oct * 8];
                float4 e0 = *(const float4*)&ep[0];
                float4 e1 = *(const float4*)&ep[4];
                float4 e2 = *(const float4*)&ep[8];
                float4 e3 = *(const float4*)&ep[12];
                float4 bi0 = *(const float4*)&bp[0];
                float4 bi1 = *(const float4*)&bp[4];
                float r0 = fmaxf(fmaf(e0.x, os0, fmaf(e0.y, os1, bi0.x)), 0.f);
                float r1 = fmaxf(fmaf(e0.z, os0, fmaf(e0.w, os1, bi0.y)), 0.f);
                float r2 = fmaxf(fmaf(e1.x, os0, fmaf(e1.y, os1, bi0.z)), 0.f);
                float r3 = fmaxf(fmaf(e1.z, os0, fmaf(e1.w, os1, bi0.w)), 0.f);
                float r4 = fmaxf(fmaf(e2.x, os0, fmaf(e2.y, os1, bi1.x)), 0.f);
                float r5 = fmaxf(fmaf(e2.z, os0, fmaf(e2.w, os1, bi1.y)), 0.f);
                float r6 = fmaxf(fmaf(e3.x, os0, fmaf(e3.y, os1, bi1.z)), 0.f);
                float r7 = fmaxf(fmaf(e3.z, os0, fmaf(e3.w, os1, bi1.w)), 0.f);
                float4 pk;
                pk.x = pkrtz(r0, r1);
                pk.y = pkrtz(r2, r3);
                pk.z = pkrtz(r4, r5);
                pk.w = pkrtz(r6, r7);
                int slot = (b ^ oct) & 15;
                *(float4*)&act_sh[(oct >> 2) * 512 + (oct & 3) * 128 + slot * 8] = pk;
            }
        }
        __syncthreads();

        // ---- phase B: MFMA, B-fragments re-loaded from L2-resident g_w4 ----
        {
            v4f c0 = {0.f, 0.f, 0.f, 0.f}, c1 = {0.f, 0.f, 0.f, 0.f};
            #pragma unroll
            for (int ks4 = 0; ks4 < 4; ++ks4) {
                v8h a  = *(const v8h*)&act_sh[a_off[ks4]];
                v8h w0 = *(const v8h*)&wp[ks4 * 32];
                v8h w1 = *(const v8h*)&wp[16 * KPAD + ks4 * 32];
                c0 = __builtin_amdgcn_mfma_f32_16x16x32_f16(a, w0, c0, 0, 0, 0);
                c1 = __builtin_amdgcn_mfma_f32_16x16x32_f16(a, w1, c1, 0, 0, 0);
            }
            *(v4f*)&part[(wv * 2 + 0) * 256 + lane * 4] = c0;
            *(v4f*)&part[(wv * 2 + 1) * 256 + lane * 4] = c1;
        }
        // ---- deriv: os += DT * (dec . act), act read from frag-major LDS ----
        #pragma unroll
        for (int ii = 0; ii < 2; ++ii) {
            int task = t + ii * NTHR;
            if (task < NOSC * NB * 2) {         // 1600 tasks
                int o = task >> 5, r = task & 31, b = r >> 1, d = r & 1;
                const _Float16* dr = &dec_sh[(o * 2 + d) * 40];
                float acc0 = 0.f, acc1 = 0.f;
                #pragma unroll
                for (int c = 0; c < 5; ++c) {
                    int oct = o * 5 + c;
                    int base = (oct >> 2) * 512 + (oct & 3) * 128 + (((b ^ oct) & 15) * 8);
                    float4 af = *(const float4*)&act_sh[base];
                    float4 df = *(const float4*)&dr[c * 8];
                    acc0 = fdot2f(af.x, df.x, acc0);
                    acc1 = fdot2f(af.y, df.y, acc1);
                    acc0 = fdot2f(af.z, df.z, acc0);
                    acc1 = fdot2f(af.w, df.w, acc1);
                }
                os_sh[o * 32 + r] += 0.001f * (acc0 + acc1);
            }
        }
        __syncthreads();

        // ---- R: reduce MFMA partials over 16 waves -> b1 ----
        if (t < 512) {
            int b = t & 15, j = t >> 4;         // b 0..15, j 0..31
            int base = (j >> 4) * 256 + (b >> 2) * 64 + (j & 15) * 4 + (b & 3);
            float sum = 0.f;
            #pragma unroll
            for (int w = 0; w < 16; ++w)
                sum += part[w * 512 + base];
            b1s[b * B1STR + j] = fmaxf(sum + fc4_b[j], 0.f);
        }
        __syncthreads();

        // ---- phase C: fc5 + limb ODE + stores (threads 0..15) ----
        if (t < NB) {
            float a0 = bs0, a1 = bs1;
            #pragma unroll
            for (int i = 0; i < 32; i += 4) {
                float4 bv = *(const float4*)&b1s[t * B1STR + i];
                a0 = dot4(bv, *(const float4*)&fc5_w[i],      a0);
                a1 = dot4(bv, *(const float4*)&fc5_w[32 + i], a1);
            }
            float f1v = fmaxf(a0, 0.f) * 50.f * fmaxf(l1 - 0.05f, 0.f);
            float f2v = fmaxf(a1, 0.f) * 50.f * fmaxf(l2 - 0.05f, 0.f);
            float domega = (0.02f * (f2v - f1v) - 0.01f * omega) / 0.001f;
            float dl1 = ((0.1f - 0.02f * theta) - l1) / 0.05f;
            float dl2 = ((0.1f + 0.02f * theta) - l2) / 0.05f;
            float pos = fmaf(0.001f, omega,  theta);
            float vel = fmaf(0.001f, domega, omega);
            l1 = fmaf(0.001f, dl1, l1);
            l2 = fmaf(0.001f, dl2, l2);
            bool inb = (pos > -HALF_PI) && (pos < HALF_PI);
            float posc = fminf(fmaxf(pos, -HALF_PI), HALF_PI);
            vel = inb ? vel : 0.f;
            theta = posc;
            omega = vel;
            float4 lo; lo.x = posc; lo.y = vel; lo.z = l1; lo.w = l2;
            *(float4*)&out[((size_t)s * BATCH + (b0 + t)) * 4] = lo;
            float2 ao; ao.x = a0; ao.y = a1;
            *(float2*)&out[ACT_OFF + ((size_t)s * BATCH + (b0 + t)) * 2] = ao;
        }
        __syncthreads();
    }
}

extern "C" void kernel_launch(void* const* d_in, const int* in_sizes, int n_in,
                              void* d_out, int out_size, void* d_ws, size_t ws_size,
                              hipStream_t stream) {
    (void)in_sizes; (void)n_in; (void)d_ws; (void)ws_size; (void)out_size;
    const float* x_     = (const float*)d_in[0];
    const float* fc1_w  = (const float*)d_in[1];
    const float* fc1_b  = (const float*)d_in[2];
    const float* fc2_w  = (const float*)d_in[3];
    const float* fc2_b  = (const float*)d_in[4];
    const float* fc3_w  = (const float*)d_in[5];
    const float* fc3_b  = (const float*)d_in[6];
    const float* fcd_w  = (const float*)d_in[7];
    const float* fcd_b  = (const float*)d_in[8];
    const float* enc    = (const float*)d_in[9];
    const float* oscb   = (const float*)d_in[10];
    const float* dec    = (const float*)d_in[11];
    const float* fc4_w  = (const float*)d_in[12];
    const float* fc4_b  = (const float*)d_in[13];
    const float* fc5_w  = (const float*)d_in[14];
    const float* fc5_b  = (const float*)d_in[15];
    float* out = (float*)d_out;

    hipLaunchKernelGGL(prep_f16, dim3(256), dim3(256), 0, stream, fc4_w);
    hipLaunchKernelGGL(net_main, dim3(BATCH / NB), dim3(NTHR), 0, stream,
                       x_, fc1_w, fc1_b, fc2_w, fc2_b, fc3_w, fc3_b,
                       fcd_w, fcd_b, enc, oscb, dec, fc4_b,
                       fc5_w, fc5_b, out);
}